// Round 1
// baseline (592.415 us; speedup 1.0000x reference)
//
#include <hip/hip_runtime.h>
#include <hip/hip_bf16.h>

// BondUpdateLayer fused kernel (MI355X / gfx950)
// x = concat([bond, atom[a0], atom[a1], glob[g]]) (256)
// out = (softplus(softplus(x@W1+b1)@W2+b2))@W3+b3   (32), fp32 out
// bf16 MFMA 16x16x32, fp32 accumulate. One wave = 16 bonds, block = 64 bonds.
// R1: weights staged in LDS once per block (was: 44 global 16B reads/wave,
//     2.8 GB of L2-serviced weight traffic). All B-fragments now ds_read_b128.

typedef __bf16 bf16x8 __attribute__((ext_vector_type(8)));
typedef float  floatx4 __attribute__((ext_vector_type(4)));

#define W1_OFF 0
#define W2_OFF 16384
#define W3_OFF 20480
#define W_TOTAL 22528   // bf16 elements: 256*64 + 64*64 + 64*32
#define H_LDS 4096      // 4 waves * 2 ksteps * 64 lanes * 8 bf16 (transpose strips)

// Convert W1/W2/W3 (fp32, row-major KxN) into bf16 B-fragment order:
// dst[((kstep*ntiles + tile)*64 + quad*16 + (n&15))*8 + (k&7)]
// so a lane's 8 B values for one MFMA are one contiguous 16B load.
__global__ void prep_weights(const float* __restrict__ W1,
                             const float* __restrict__ W2,
                             const float* __restrict__ W3,
                             __bf16* __restrict__ dst) {
  int tid = blockIdx.x * 256 + threadIdx.x;
  if (tid < 16384) {            // W1: 256x64
    int k = tid >> 6, n = tid & 63;
    int d = W1_OFF + ((((k >> 5) * 4 + (n >> 4)) * 64) + ((k >> 3) & 3) * 16 + (n & 15)) * 8 + (k & 7);
    dst[d] = (__bf16)W1[tid];
  } else if (tid < 20480) {     // W2: 64x64
    int t2 = tid - 16384;
    int k = t2 >> 6, n = t2 & 63;
    int d = W2_OFF + ((((k >> 5) * 4 + (n >> 4)) * 64) + ((k >> 3) & 3) * 16 + (n & 15)) * 8 + (k & 7);
    dst[d] = (__bf16)W2[t2];
  } else if (tid < W_TOTAL) {   // W3: 64x32
    int t3 = tid - 20480;
    int k = t3 >> 5, n = t3 & 31;
    int d = W3_OFF + ((((k >> 5) * 2 + (n >> 4)) * 64) + ((k >> 3) & 3) * 16 + (n & 15)) * 8 + (k & 7);
    dst[d] = (__bf16)W3[t3];
  }
}

__device__ __forceinline__ float softplus_f(float v) {
  // = max(v,0) + log1p(exp(-|v|)); arg of log is in (1,2], no cancellation
  return fmaxf(v, 0.0f) + __logf(1.0f + __expf(-fabsf(v)));
}

template <bool USE_WS>
__global__ __launch_bounds__(256, 3)
void bond_update(const float* __restrict__ bond,
                 const float* __restrict__ atom,
                 const float* __restrict__ glob,
                 const int* __restrict__ atom_idx,
                 const int* __restrict__ global_idx,
                 const float* __restrict__ gW1, const float* __restrict__ b1,
                 const float* __restrict__ gW2, const float* __restrict__ b2,
                 const float* __restrict__ gW3, const float* __restrict__ b3,
                 const __bf16* __restrict__ wsW,
                 float* __restrict__ out) {
  extern __shared__ __bf16 smem[];
  __bf16* sW = smem;             // frag-ordered weights, 22528 bf16 = 45056 B
  __bf16* sH = smem + W_TOTAL;   // transpose strips, 4096 bf16, wave-private

  const int tid  = threadIdx.x;
  const int lane = tid & 63;
  const int wave = tid >> 6;
  const int m    = lane & 15;   // row within 16-row strip / output col within tile
  const int q    = lane >> 4;   // quad

  const int row0 = blockIdx.x * 64 + wave * 16;  // strip base
  const int row  = row0 + m;

  // ---- gather indices (issue ASAP; gathers depend on them) ----
  const int2 aa = *(const int2*)(atom_idx + 2 * row);
  const int  gg = global_idx[row];

  // ---- stage frag-ordered weights into LDS (once per block) ----
  if constexpr (USE_WS) {
    // 22528 bf16 / 8 = 2816 contiguous 16B groups; 2816 = 11 * 256.
    #pragma unroll
    for (int i = 0; i < 11; ++i) {
      int g = i * 256 + tid;
      *(bf16x8*)(sW + (size_t)g * 8) = *(const bf16x8*)(wsW + (size_t)g * 8);
    }
  } else {
    // Fallback: convert fp32 global weights into frag order in LDS.
    for (int g = tid; g < 2816; g += 256) {   // groups of 8 consecutive k
      const float* Ws; int N, gl, dbase, nt4;
      if (g < 2048)      { Ws = gW1; N = 64; gl = g;        dbase = W1_OFF; nt4 = 1; }
      else if (g < 2560) { Ws = gW2; N = 64; gl = g - 2048; dbase = W2_OFF; nt4 = 1; }
      else               { Ws = gW3; N = 32; gl = g - 2560; dbase = W3_OFF; nt4 = 0; }
      int lanec = gl & 63;
      int tk    = gl >> 6;
      int tile  = nt4 ? (tk & 3) : (tk & 1);
      int kstep = nt4 ? (tk >> 2) : (tk >> 1);
      int k0 = kstep * 32 + (lanec >> 4) * 8;
      int n  = tile * 16 + (lanec & 15);
      bf16x8 f;
      #pragma unroll
      for (int j = 0; j < 8; ++j) f[j] = (__bf16)Ws[(k0 + j) * N + n];
      *(bf16x8*)(sW + dbase + gl * 8) = f;
    }
  }

  const float* src0 = bond + (size_t)row * 64;
  const float* src1 = atom + (size_t)aa.x * 64;
  const float* src2 = atom + (size_t)aa.y * 64;
  const float* src3 = glob + (size_t)gg * 64;

  // ---- bias preloads (overlap with gathers/staging) ----
  float bv1[4], bv2[4], bv3[2];
  #pragma unroll
  for (int t = 0; t < 4; ++t) { bv1[t] = b1[t * 16 + m]; bv2[t] = b2[t * 16 + m]; }
  #pragma unroll
  for (int t = 0; t < 2; ++t) { bv3[t] = b3[t * 16 + m]; }

  // ---- gather directly into A-fragment registers ----
  // A[m=lane&15][k = ks*32 + q*8 + j]; feature segments are 64-aligned so each
  // 8-run stays inside one source row. 2x float4 per kstep per lane.
  bf16x8 A[8];
  #pragma unroll
  for (int ks = 0; ks < 8; ++ks) {
    const float* p = (ks < 2 ? src0 : ks < 4 ? src1 : ks < 6 ? src2 : src3)
                     + (ks & 1) * 32 + q * 8;
    float4 x0 = *(const float4*)p;
    float4 x1 = *(const float4*)(p + 4);
    bf16x8 f;
    f[0] = (__bf16)x0.x; f[1] = (__bf16)x0.y; f[2] = (__bf16)x0.z; f[3] = (__bf16)x0.w;
    f[4] = (__bf16)x1.x; f[5] = (__bf16)x1.y; f[6] = (__bf16)x1.z; f[7] = (__bf16)x1.w;
    A[ks] = f;
  }

  __syncthreads();   // sW ready (also drains gathers, which GEMM1 needs anyway)

  // ---- GEMM1: (16x256) @ (256x64), bias folded into acc init ----
  floatx4 acc[4];
  #pragma unroll
  for (int t = 0; t < 4; ++t) acc[t] = (floatx4){bv1[t], bv1[t], bv1[t], bv1[t]};
  #pragma unroll
  for (int ks = 0; ks < 8; ++ks) {
    #pragma unroll
    for (int t = 0; t < 4; ++t) {
      bf16x8 bf = *(const bf16x8*)(sW + W1_OFF + ((ks * 4 + t) * 64 + lane) * 8);
      acc[t] = __builtin_amdgcn_mfma_f32_16x16x32_bf16(A[ks], bf, acc[t], 0, 0, 0);
    }
  }

  // ---- epilogue1: softplus, C-layout -> A-layout via wave-private LDS ----
  __bf16* hb = sH + wave * 1024;  // 2*64*8 per wave
  #pragma unroll
  for (int t = 0; t < 4; ++t) {
    int c   = t * 16 + m;            // output col = k of next GEMM
    int ks2 = c >> 5;
    int l2b = ((c >> 3) & 3) * 16;
    int j2  = c & 7;
    #pragma unroll
    for (int r = 0; r < 4; ++r) {
      float sp = softplus_f(acc[t][r]);
      hb[((ks2 * 64) + l2b + q * 4 + r) * 8 + j2] = (__bf16)sp;  // row_l = q*4+r
    }
  }

  // ---- GEMM2: (16x64) @ (64x64) ----
  bf16x8 A2[2];
  #pragma unroll
  for (int ks = 0; ks < 2; ++ks)
    A2[ks] = *(const bf16x8*)(hb + (ks * 64 + lane) * 8);

  floatx4 acc2[4];
  #pragma unroll
  for (int t = 0; t < 4; ++t) acc2[t] = (floatx4){bv2[t], bv2[t], bv2[t], bv2[t]};
  #pragma unroll
  for (int ks = 0; ks < 2; ++ks) {
    #pragma unroll
    for (int t = 0; t < 4; ++t) {
      bf16x8 bf = *(const bf16x8*)(sW + W2_OFF + ((ks * 4 + t) * 64 + lane) * 8);
      acc2[t] = __builtin_amdgcn_mfma_f32_16x16x32_bf16(A2[ks], bf, acc2[t], 0, 0, 0);
    }
  }

  // ---- epilogue2: softplus -> same wave-private LDS strip ----
  #pragma unroll
  for (int t = 0; t < 4; ++t) {
    int c   = t * 16 + m;
    int ks2 = c >> 5;
    int l2b = ((c >> 3) & 3) * 16;
    int j2  = c & 7;
    #pragma unroll
    for (int r = 0; r < 4; ++r) {
      float sp = softplus_f(acc2[t][r]);
      hb[((ks2 * 64) + l2b + q * 4 + r) * 8 + j2] = (__bf16)sp;
    }
  }

  // ---- GEMM3: (16x64) @ (64x32) ----
  bf16x8 A3[2];
  #pragma unroll
  for (int ks = 0; ks < 2; ++ks)
    A3[ks] = *(const bf16x8*)(hb + (ks * 64 + lane) * 8);

  floatx4 acc3[2];
  #pragma unroll
  for (int t = 0; t < 2; ++t) acc3[t] = (floatx4){bv3[t], bv3[t], bv3[t], bv3[t]};
  #pragma unroll
  for (int ks = 0; ks < 2; ++ks) {
    #pragma unroll
    for (int t = 0; t < 2; ++t) {
      bf16x8 bf = *(const bf16x8*)(sW + W3_OFF + ((ks * 2 + t) * 64 + lane) * 8);
      acc3[t] = __builtin_amdgcn_mfma_f32_16x16x32_bf16(A3[ks], bf, acc3[t], 0, 0, 0);
    }
  }

  // ---- store: row = q*4+r, col = t*16+m; lanes of a quad are 64B-coalesced ----
  float* op = out + (size_t)row0 * 32;
  #pragma unroll
  for (int t = 0; t < 2; ++t)
    #pragma unroll
    for (int r = 0; r < 4; ++r)
      op[(q * 4 + r) * 32 + t * 16 + m] = acc3[t][r];
}

extern "C" void kernel_launch(void* const* d_in, const int* in_sizes, int n_in,
                              void* d_out, int out_size, void* d_ws, size_t ws_size,
                              hipStream_t stream) {
  const float* bond       = (const float*)d_in[0];
  const float* atom       = (const float*)d_in[1];
  const float* glob       = (const float*)d_in[2];
  const int*   atom_idx   = (const int*)d_in[3];
  const int*   global_idx = (const int*)d_in[4];
  const float* W1 = (const float*)d_in[5];
  const float* b1 = (const float*)d_in[6];
  const float* W2 = (const float*)d_in[7];
  const float* b2 = (const float*)d_in[8];
  const float* W3 = (const float*)d_in[9];
  const float* b3 = (const float*)d_in[10];
  float* out = (float*)d_out;

  const int n_bond = in_sizes[0] / 64;
  const int grid   = n_bond / 64;  // 1e6/64 = 15625 exact

  const size_t lds_bytes = (size_t)(W_TOTAL + H_LDS) * sizeof(__bf16);  // 53248

  const bool use_ws = (ws_size >= (size_t)W_TOTAL * sizeof(__bf16)) && d_ws != nullptr;
  if (use_ws) {
    __bf16* wsW = (__bf16*)d_ws;
    prep_weights<<<(W_TOTAL + 255) / 256, 256, 0, stream>>>(W1, W2, W3, wsW);
    bond_update<true><<<grid, 256, lds_bytes, stream>>>(
        bond, atom, glob, atom_idx, global_idx,
        W1, b1, W2, b2, W3, b3, wsW, out);
  } else {
    bond_update<false><<<grid, 256, lds_bytes, stream>>>(
        bond, atom, glob, atom_idx, global_idx,
        W1, b1, W2, b2, W3, b3, (const __bf16*)nullptr, out);
  }
}